// Round 1
// baseline (44176.044 us; speedup 1.0000x reference)
//
#include <hip/hip_runtime.h>

// Problem constants
#define SEQ   8192
#define VOCAB 256
#define HID   2048
#define ODIM  256
#define NBLK  256   // persistent blocks (1 per CU)
#define NTHR  512   // 8 waves per block
#define JPB   8     // hidden columns owned per block (HID/NBLK)

// ---------------------------------------------------------------------------
// K0: zero h double-buffer + barrier flags (ws is poisoned 0xAA before every
// timed call, so this must run every launch).
// ---------------------------------------------------------------------------
__global__ void k_init(float* p) {
    int i = blockIdx.x * blockDim.x + threadIdx.x;
    if (i < 2 * HID + NBLK) p[i] = 0.f;
}

// ---------------------------------------------------------------------------
// K1: Zv[v][gate][j] = emb[v] @ W_gate[:,j] + b_gate[j] + c_gate[j]
// Only 256 distinct x values exist, so the whole input projection is an
// 8 MB lookup table. grid = (8 v-tiles, 8 col-tiles), 256 threads.
// ---------------------------------------------------------------------------
__global__ void k_zv(const float* __restrict__ emb, const float* __restrict__ W,
                     const float* __restrict__ bb, const float* __restrict__ cb,
                     float* __restrict__ Zv, int gate) {
    __shared__ float e[32][VOCAB];   // 32 KB emb tile
    const int tid = threadIdx.x;
    const int vt = blockIdx.x, ct = blockIdx.y;
    for (int r = 0; r < 32; ++r)
        e[r][tid] = emb[(size_t)(vt * 32 + r) * VOCAB + tid];
    __syncthreads();
    const int j = ct * 256 + tid;                // 0..2047
    const float bias = bb[j] + cb[j];
    float acc[32];
#pragma unroll
    for (int r = 0; r < 32; ++r) acc[r] = 0.f;
    for (int u = 0; u < VOCAB; ++u) {
        float w = W[(size_t)u * HID + j];        // coalesced
#pragma unroll
        for (int r = 0; r < 32; ++r) acc[r] += e[r][u] * w;   // LDS broadcast
    }
    for (int r = 0; r < 32; ++r)
        Zv[(size_t)(vt * 32 + r) * (4 * HID) + (size_t)gate * HID + j] = acc[r] + bias;
}

// ---------------------------------------------------------------------------
// K2: persistent cooperative LSTM. Block b owns hidden columns [8b, 8b+8)
// of all 4 gates. U slices live in REGISTERS (128 VGPR/thread). Per step:
//   h(t-1) (8 KB) -> LDS via agent-coherent loads; register matvec;
//   LDS reduction; gates on 8 lanes; publish h via agent-coherent stores;
//   store-only flag barrier (no RMW contention).
// Thread layout: gate = tid&3, rowseg rs = tid>>2 (16 rows each).
// ---------------------------------------------------------------------------
__launch_bounds__(NTHR, 2)
__global__ void k_lstm(const float* __restrict__ Uii, const float* __restrict__ Uff,
                       const float* __restrict__ Ugg, const float* __restrict__ Uoo,
                       const float* __restrict__ Zv,  const int* __restrict__ x,
                       float* hbuf, unsigned* flags, float* __restrict__ hs,
                       float* __restrict__ outTail) {
    // h stored padded: row r at hpad[(r>>4)*20 + (r&15)]  (16 rows + 4 pad) to
    // keep the 4-lane-broadcast float4 matvec reads at <=2 addrs/bank.
    __shared__ float hpad[128 * 20];        // 10 KB
    __shared__ float scratch[128 * 36];     // 18 KB partials [seg][col], pad 36 keeps f4 stores aligned
    __shared__ float scratch2[8 * 32];      // per-wave column sums
    __shared__ float c_lds[JPB];            // cell state for this block's 8 columns

    const int tid  = threadIdx.x;
    const int b    = blockIdx.x;
    const int gate = tid & 3;
    const int rs   = tid >> 2;              // 0..127
    const int lane = tid & 63;
    const int wv   = tid >> 6;

    const float* Ug = (gate == 0) ? Uii : (gate == 1) ? Uff : (gate == 2) ? Ugg : Uoo;

    // Load this thread's U slice into registers (rows rs*16..+16, cols 8b..8b+8)
    float u[16][JPB];
#pragma unroll
    for (int r = 0; r < 16; ++r) {
        const float4* p = (const float4*)(Ug + (size_t)(rs * 16 + r) * HID + b * JPB);
        float4 a0 = p[0], a1 = p[1];
        u[r][0] = a0.x; u[r][1] = a0.y; u[r][2] = a0.z; u[r][3] = a0.w;
        u[r][4] = a1.x; u[r][5] = a1.y; u[r][6] = a1.z; u[r][7] = a1.w;
    }
    if (tid < JPB) c_lds[tid] = 0.f;

    float4* hp4 = (float4*)hpad;
    unsigned budget = 1u << 22;             // watchdog: bounded spin, avoids hard hang

    for (int t = 0; t < SEQ; ++t) {
        if (t > 0) {
            if (wv == 0) {                  // wave 0 polls all 256 flags, 4 per lane
                const unsigned tgt = (unsigned)t;
                for (;;) {
                    unsigned m0 = __hip_atomic_load(&flags[lane      ], __ATOMIC_RELAXED, __HIP_MEMORY_SCOPE_AGENT);
                    unsigned m1 = __hip_atomic_load(&flags[lane +  64], __ATOMIC_RELAXED, __HIP_MEMORY_SCOPE_AGENT);
                    unsigned m2 = __hip_atomic_load(&flags[lane + 128], __ATOMIC_RELAXED, __HIP_MEMORY_SCOPE_AGENT);
                    unsigned m3 = __hip_atomic_load(&flags[lane + 192], __ATOMIC_RELAXED, __HIP_MEMORY_SCOPE_AGENT);
                    bool ok = (m0 >= tgt) & (m1 >= tgt) & (m2 >= tgt) & (m3 >= tgt);
                    if (__all((int)ok) || budget == 0) break;
                    --budget;
                    __builtin_amdgcn_s_sleep(1);
                }
            }
            __syncthreads();
        }

        // Prefetch the x-dependent gate bias early (off the critical path).
        float zx = 0.f;
        if (wv == 0) {
            const int cc = lane & 31;       // col = (cc>>3)=gate, (cc&7)=j
            const int xt = x[t];
            zx = Zv[(size_t)xt * (4 * HID) + (size_t)(cc >> 3) * HID + b * JPB + (cc & 7)];
        }

        // Broadcast h(t-1): coherent global load (bypasses stale L2) -> padded LDS
        {
            const float* hb = hbuf + (size_t)(t & 1) * HID + tid * 4;
            unsigned long long r0 = __hip_atomic_load((const unsigned long long*)hb,       __ATOMIC_RELAXED, __HIP_MEMORY_SCOPE_AGENT);
            unsigned long long r1 = __hip_atomic_load((const unsigned long long*)(hb + 2), __ATOMIC_RELAXED, __HIP_MEMORY_SCOPE_AGENT);
            float* dst = hpad + (tid >> 2) * 20 + (tid & 3) * 4;
            ((unsigned long long*)dst)[0] = r0;
            ((unsigned long long*)dst)[1] = r1;
        }
        __syncthreads();

        // Register matvec: acc[jj] = sum over this thread's 16 rows
        float acc[JPB];
#pragma unroll
        for (int jj = 0; jj < JPB; ++jj) acc[jj] = 0.f;
#pragma unroll
        for (int k = 0; k < 4; ++k) {
            float4 h4 = hp4[rs * 5 + k];
            float hv[4] = {h4.x, h4.y, h4.z, h4.w};
#pragma unroll
            for (int i = 0; i < 4; ++i)
#pragma unroll
                for (int jj = 0; jj < JPB; ++jj)
                    acc[jj] += hv[i] * u[k * 4 + i][jj];
        }
        {
            float4* s4 = (float4*)(scratch + rs * 36 + gate * JPB);
            s4[0] = make_float4(acc[0], acc[1], acc[2], acc[3]);
            s4[1] = make_float4(acc[4], acc[5], acc[6], acc[7]);
        }
        __syncthreads();

        // Reduce 128 row-segments per column: 8 serial + xor32 + per-wave slot
        {
            const int c  = tid & 31;
            const int sg = tid >> 5;        // 0..15
            float v = 0.f;
#pragma unroll
            for (int k = 0; k < 8; ++k) v += scratch[(sg * 8 + k) * 36 + c];
            v += __shfl_xor(v, 32);
            if (lane < 32) scratch2[wv * 32 + c] = v;
        }
        __syncthreads();

        if (wv == 0) {
            const int cc = lane & 31;
            float z = 0.f;
#pragma unroll
            for (int w2 = 0; w2 < 8; ++w2) z += scratch2[w2 * 32 + cc];
            const float zfull = z + zx;
            const int jj = lane & 7;
            float zi = __shfl(zfull, jj);
            float zf = __shfl(zfull, 8 + jj);
            float zg = __shfl(zfull, 16 + jj);
            float zo = __shfl(zfull, 24 + jj);
            if (lane < JPB) {
                float ig = 1.f / (1.f + __expf(-zi));
                float fg = 1.f / (1.f + __expf(-zf));
                float gg = tanhf(zg);
                float og = 1.f / (1.f + __expf(-zo));
                float cn = fg * c_lds[lane] + ig * gg;
                float hn = og * tanhf(cn);
                c_lds[lane] = cn;
                const int jg = b * JPB + lane;
                hs[(size_t)t * HID + jg] = hn;                       // normal store, read post-kernel
                __hip_atomic_store(&hbuf[(size_t)((t + 1) & 1) * HID + jg], hn,
                                   __ATOMIC_RELAXED, __HIP_MEMORY_SCOPE_AGENT);
                if (t == SEQ - 1) { outTail[jg] = hn; outTail[HID + jg] = cn; }
            }
            if (lane == 0) {
                // drain h stores to the coherence point BEFORE publishing the flag
                asm volatile("s_waitcnt vmcnt(0)" ::: "memory");
                __hip_atomic_store(&flags[b], (unsigned)(t + 1),
                                   __ATOMIC_RELAXED, __HIP_MEMORY_SCOPE_AGENT);
            }
        }
    }
}

// ---------------------------------------------------------------------------
// K3: out[t][o] = hs[t] @ V_w[:,o] + V_b[o]. 256 blocks x 256 threads,
// 32-row tiles, K tiled by 64 through LDS. fp32 VALU (~55us floor).
// ---------------------------------------------------------------------------
__global__ void k_out(const float* __restrict__ hs, const float* __restrict__ Vw,
                      const float* __restrict__ Vb, float* __restrict__ out) {
    __shared__ float tile[32][64];          // 8 KB
    const int tid = threadIdx.x;            // 256: one output column each
    const int t0 = blockIdx.x * 32;
    float acc[32];
#pragma unroll
    for (int r = 0; r < 32; ++r) acc[r] = 0.f;
    for (int k0 = 0; k0 < HID; k0 += 64) {
        {
            const int r = tid >> 3, kk = (tid & 7) * 8;
            const float4* p = (const float4*)(hs + (size_t)(t0 + r) * HID + k0 + kk);
            float4 a = p[0], bq = p[1];
            *(float4*)&tile[r][kk]     = a;
            *(float4*)&tile[r][kk + 4] = bq;
        }
        __syncthreads();
        for (int kk = 0; kk < 64; ++kk) {
            float w = Vw[(size_t)(k0 + kk) * ODIM + tid];   // coalesced, L2-hot
#pragma unroll
            for (int r = 0; r < 32; ++r) acc[r] += tile[r][kk] * w;  // LDS broadcast
        }
        __syncthreads();
    }
    const float vb = Vb[tid];
    for (int r = 0; r < 32; ++r)
        out[(size_t)(t0 + r) * ODIM + tid] = acc[r] + vb;
}

// ---------------------------------------------------------------------------
extern "C" void kernel_launch(void* const* d_in, const int* in_sizes, int n_in,
                              void* d_out, int out_size, void* d_ws, size_t ws_size,
                              hipStream_t stream) {
    const int*   x   = (const int*)d_in[0];
    const float* emb = (const float*)d_in[1];
    const float* W[4] = {(const float*)d_in[2], (const float*)d_in[6],
                         (const float*)d_in[10], (const float*)d_in[14]};
    const float* B[4] = {(const float*)d_in[3], (const float*)d_in[7],
                         (const float*)d_in[11], (const float*)d_in[15]};
    const float* U[4] = {(const float*)d_in[4], (const float*)d_in[8],
                         (const float*)d_in[12], (const float*)d_in[16]};
    const float* C[4] = {(const float*)d_in[5], (const float*)d_in[9],
                         (const float*)d_in[13], (const float*)d_in[17]};
    const float* Vw = (const float*)d_in[18];
    const float* Vb = (const float*)d_in[19];
    float* out = (float*)d_out;

    // ws layout (floats): Zv[256*4*2048] | hs[8192*2048] | hbuf[2*2048] | flags[256]
    float* ws   = (float*)d_ws;
    float* Zv   = ws;
    float* hs   = Zv + (size_t)VOCAB * 4 * HID;
    float* hbuf = hs + (size_t)SEQ * HID;
    unsigned* flags = (unsigned*)(hbuf + 2 * HID);
    // total ~75.6 MB

    k_init<<<dim3(9), dim3(512), 0, stream>>>(hbuf);
    for (int g = 0; g < 4; ++g)
        k_zv<<<dim3(8, 8), dim3(256), 0, stream>>>(emb, W[g], B[g], C[g], Zv, g);

    float* outTail = out + (size_t)SEQ * ODIM;
    const float *Ui = U[0], *Uf = U[1], *Ugp = U[2], *Uo = U[3];
    const float* Zvc = Zv; const int* xc = x;
    float* hbufc = hbuf; unsigned* flagsc = flags; float* hsc = hs; float* ot = outTail;
    void* args[10] = {&Ui, &Uf, &Ugp, &Uo, &Zvc, &xc, &hbufc, &flagsc, &hsc, &ot};
    hipLaunchCooperativeKernel((void*)k_lstm, dim3(NBLK), dim3(NTHR), args, 0, stream);

    k_out<<<dim3(256), dim3(256), 0, stream>>>(hs, Vw, Vb, out);
}

// Round 2
// 35962.793 us; speedup vs baseline: 1.2284x; 1.2284x over previous
//
#include <hip/hip_runtime.h>

// Problem constants
#define SEQ   8192
#define VOCAB 256
#define HID   2048
#define ODIM  256
#define NBLK  256   // persistent blocks (1 per CU)
#define NTHR  512   // 8 waves per block
#define JPB   8     // hidden columns owned per block (HID/NBLK)

// Fast gate math: v_exp_f32 + v_rcp_f32 (~1ulp each; threshold is bf16-scale)
__device__ __forceinline__ float fsigmoid(float x) {
    return __builtin_amdgcn_rcpf(1.f + __expf(-x));   // large |x| limits are exact (inf->0)
}
__device__ __forceinline__ float ftanh(float x) {
    x = fminf(20.f, fmaxf(-20.f, x));                 // avoid inf*0 NaN at |x|>44
    float e = __expf(2.f * x);
    return (e - 1.f) * __builtin_amdgcn_rcpf(e + 1.f);
}

// ---------------------------------------------------------------------------
// K1: Zv[v][gate][j] = emb[v] @ W_gate[:,j] + b_gate[j] + c_gate[j]
// Only 256 distinct x values exist, so the whole input projection is an
// 8 MB lookup table. grid = (8 v-tiles, 8 col-tiles), 256 threads.
// ---------------------------------------------------------------------------
__global__ void k_zv(const float* __restrict__ emb, const float* __restrict__ W,
                     const float* __restrict__ bb, const float* __restrict__ cb,
                     float* __restrict__ Zv, int gate) {
    __shared__ float e[32][VOCAB];   // 32 KB emb tile
    const int tid = threadIdx.x;
    const int vt = blockIdx.x, ct = blockIdx.y;
    for (int r = 0; r < 32; ++r)
        e[r][tid] = emb[(size_t)(vt * 32 + r) * VOCAB + tid];
    __syncthreads();
    const int j = ct * 256 + tid;                // 0..2047
    const float bias = bb[j] + cb[j];
    float acc[32];
#pragma unroll
    for (int r = 0; r < 32; ++r) acc[r] = 0.f;
    for (int u = 0; u < VOCAB; ++u) {
        float w = W[(size_t)u * HID + j];        // coalesced
#pragma unroll
        for (int r = 0; r < 32; ++r) acc[r] += e[r][u] * w;   // LDS broadcast
    }
    for (int r = 0; r < 32; ++r)
        Zv[(size_t)(vt * 32 + r) * (4 * HID) + (size_t)gate * HID + j] = acc[r] + bias;
}

// ---------------------------------------------------------------------------
// K2: persistent cooperative LSTM. Block b owns hidden columns [8b, 8b+8).
// U slices live in registers (128 f32/thread). Cross-block h exchange uses
// fused (h, epoch) 8-byte atomic pairs, double-buffered by step parity:
// one LLC transaction = flag check + data. No producer waitcnt, no separate
// flag array, no bulk h reload round.
//   step t: every thread spins on its 4 pairs (slot t&1, epoch==t) ->
//   LDS h -> register matvec -> wave butterfly reduce -> wave0 gates ->
//   wave0 lanes 0-7 publish (h, t+1) pairs to slot (t+1)&1.
// ---------------------------------------------------------------------------
__launch_bounds__(NTHR, 2)
__global__ void k_lstm(const float* __restrict__ Uii, const float* __restrict__ Uff,
                       const float* __restrict__ Ugg, const float* __restrict__ Uoo,
                       const float* __restrict__ Zv,  const int* __restrict__ x,
                       unsigned long long* pub, float* __restrict__ hs,
                       float* __restrict__ outTail) {
    // h padded: col c at hpad[(c>>4)*20 + (c&15)] so float4 matvec reads stay
    // <=2 addrs/bank (free on CDNA4).
    __shared__ __align__(16) float hpad[128 * 20];   // 10 KB
    __shared__ __align__(16) float scr2[8 * 32];     // per-wave per-gate column sums

    const int tid  = threadIdx.x;
    const int b    = blockIdx.x;
    const int gate = tid & 3;
    const int rs   = tid >> 2;              // 0..127: rows [16rs,16rs+16)
    const int lane = tid & 63;
    const int wv   = tid >> 6;

    const float* Ug = (gate == 0) ? Uii : (gate == 1) ? Uff : (gate == 2) ? Ugg : Uoo;

    // U slice -> registers (rows rs*16..+16, cols 8b..8b+8) = 128 VGPR/AGPR
    float u[16][JPB];
#pragma unroll
    for (int r = 0; r < 16; ++r) {
        const float4* p = (const float4*)(Ug + (size_t)(rs * 16 + r) * HID + b * JPB);
        float4 a0 = p[0], a1 = p[1];
        u[r][0] = a0.x; u[r][1] = a0.y; u[r][2] = a0.z; u[r][3] = a0.w;
        u[r][4] = a1.x; u[r][5] = a1.y; u[r][6] = a1.z; u[r][7] = a1.w;
    }

    float4* hp4 = (float4*)hpad;
    float creg = 0.f;                       // cell state, wave0 lanes 0-7
    unsigned budget = 1u << 21;             // watchdog: bounded spin, fails loudly

    for (int t = 0; t < SEQ; ++t) {
        // --- Zv prefetch (independent of h; overlaps the spin) -------------
        float zx = 0.f;
        if (wv == 0 && lane < 32) {
            const int xt = x[t];
            zx = Zv[(size_t)xt * (4 * HID) + (size_t)(lane >> 3) * HID + b * JPB + (lane & 7)];
        }

        // --- acquire h(t-1): spin on own 4 (h,epoch) pairs -----------------
        float4 hv;
        if (t == 0) {
            hv = make_float4(0.f, 0.f, 0.f, 0.f);
        } else {
            const unsigned tgt = (unsigned)t;
            const unsigned long long* sl = pub + (size_t)(t & 1) * HID + tid * 4;
            unsigned long long a0, a1, a2, a3;
            for (;;) {
                a0 = __hip_atomic_load(sl + 0, __ATOMIC_RELAXED, __HIP_MEMORY_SCOPE_AGENT);
                a1 = __hip_atomic_load(sl + 1, __ATOMIC_RELAXED, __HIP_MEMORY_SCOPE_AGENT);
                a2 = __hip_atomic_load(sl + 2, __ATOMIC_RELAXED, __HIP_MEMORY_SCOPE_AGENT);
                a3 = __hip_atomic_load(sl + 3, __ATOMIC_RELAXED, __HIP_MEMORY_SCOPE_AGENT);
                if ((unsigned)(a0 >> 32) == tgt && (unsigned)(a1 >> 32) == tgt &&
                    (unsigned)(a2 >> 32) == tgt && (unsigned)(a3 >> 32) == tgt) break;
                if (budget == 0) break;     // deadlock guard -> wrong output, loud fail
                --budget;
                __builtin_amdgcn_s_sleep(1);
            }
            hv.x = __uint_as_float((unsigned)a0);
            hv.y = __uint_as_float((unsigned)a1);
            hv.z = __uint_as_float((unsigned)a2);
            hv.w = __uint_as_float((unsigned)a3);
        }
        // h cols [4*tid, 4*tid+4) -> padded LDS
        *(float4*)&hpad[(tid >> 2) * 20 + (tid & 3) * 4] = hv;
        __syncthreads();

        // --- register matvec: 16 rows x 8 cols per thread ------------------
        float acc[JPB];
#pragma unroll
        for (int jj = 0; jj < JPB; ++jj) acc[jj] = 0.f;
#pragma unroll
        for (int k = 0; k < 4; ++k) {
            float4 h4 = hp4[rs * 5 + k];
            float hvv[4] = {h4.x, h4.y, h4.z, h4.w};
#pragma unroll
            for (int i = 0; i < 4; ++i)
#pragma unroll
                for (int jj = 0; jj < JPB; ++jj)
                    acc[jj] += hvv[i] * u[k * 4 + i][jj];
        }

        // --- in-wave butterfly over rs-local (bits 2..5), gate preserved ---
#pragma unroll
        for (int m = 4; m <= 32; m <<= 1)
#pragma unroll
            for (int jj = 0; jj < JPB; ++jj)
                acc[jj] += __shfl_xor(acc[jj], m, 64);
        if (lane < 4) {                     // lane==gate holds this wave's sums
            float4* p = (float4*)&scr2[wv * 32 + lane * 8];
            p[0] = make_float4(acc[0], acc[1], acc[2], acc[3]);
            p[1] = make_float4(acc[4], acc[5], acc[6], acc[7]);
        }
        __syncthreads();

        // --- wave0: cross-wave reduce + gates + publish --------------------
        if (wv == 0) {
            float z = 0.f;
            if (lane < 32) {
#pragma unroll
                for (int w = 0; w < 8; ++w) z += scr2[w * 32 + lane];
                z += zx;                    // x-projection + biases
            }
            const int jj = lane & 7;
            float zi = __shfl(z, jj);
            float zf = __shfl(z, 8 + jj);
            float zg = __shfl(z, 16 + jj);
            float zo = __shfl(z, 24 + jj);
            if (lane < JPB) {
                float ig = fsigmoid(zi);
                float fg = fsigmoid(zf);
                float gg = ftanh(zg);
                float og = fsigmoid(zo);
                float cn = fg * creg + ig * gg;
                float hn = og * ftanh(cn);
                creg = cn;
                const int jg = b * JPB + lane;
                hs[(size_t)t * HID + jg] = hn;               // for k_out, fire & forget
                unsigned long long pk =
                    ((unsigned long long)(unsigned)(t + 1) << 32) | __float_as_uint(hn);
                __hip_atomic_store(&pub[(size_t)((t + 1) & 1) * HID + jg], pk,
                                   __ATOMIC_RELAXED, __HIP_MEMORY_SCOPE_AGENT);
                if (t == SEQ - 1) { outTail[jg] = hn; outTail[HID + jg] = cn; }
            }
        }
    }
}

// ---------------------------------------------------------------------------
// K3: out[t][o] = hs[t] @ V_w[:,o] + V_b[o]. 256 blocks x 256 threads,
// 32-row tiles, K tiled by 64 through LDS. fp32 VALU (~60us floor).
// ---------------------------------------------------------------------------
__global__ void k_out(const float* __restrict__ hs, const float* __restrict__ Vw,
                      const float* __restrict__ Vb, float* __restrict__ out) {
    __shared__ float tile[32][64];          // 8 KB
    const int tid = threadIdx.x;            // 256: one output column each
    const int t0 = blockIdx.x * 32;
    float acc[32];
#pragma unroll
    for (int r = 0; r < 32; ++r) acc[r] = 0.f;
    for (int k0 = 0; k0 < HID; k0 += 64) {
        {
            const int r = tid >> 3, kk = (tid & 7) * 8;
            const float4* p = (const float4*)(hs + (size_t)(t0 + r) * HID + k0 + kk);
            float4 a = p[0], bq = p[1];
            *(float4*)&tile[r][kk]     = a;
            *(float4*)&tile[r][kk + 4] = bq;
        }
        __syncthreads();
        for (int kk = 0; kk < 64; ++kk) {
            float w = Vw[(size_t)(k0 + kk) * ODIM + tid];   // coalesced, L2-hot
#pragma unroll
            for (int r = 0; r < 32; ++r) acc[r] += tile[r][kk] * w;  // LDS broadcast
        }
        __syncthreads();
    }
    const float vb = Vb[tid];
    for (int r = 0; r < 32; ++r)
        out[(size_t)(t0 + r) * ODIM + tid] = acc[r] + vb;
}

// ---------------------------------------------------------------------------
extern "C" void kernel_launch(void* const* d_in, const int* in_sizes, int n_in,
                              void* d_out, int out_size, void* d_ws, size_t ws_size,
                              hipStream_t stream) {
    const int*   x   = (const int*)d_in[0];
    const float* emb = (const float*)d_in[1];
    const float* W[4] = {(const float*)d_in[2], (const float*)d_in[6],
                         (const float*)d_in[10], (const float*)d_in[14]};
    const float* B[4] = {(const float*)d_in[3], (const float*)d_in[7],
                         (const float*)d_in[11], (const float*)d_in[15]};
    const float* U[4] = {(const float*)d_in[4], (const float*)d_in[8],
                         (const float*)d_in[12], (const float*)d_in[16]};
    const float* C[4] = {(const float*)d_in[5], (const float*)d_in[9],
                         (const float*)d_in[13], (const float*)d_in[17]};
    const float* Vw = (const float*)d_in[18];
    const float* Vb = (const float*)d_in[19];
    float* out = (float*)d_out;

    // ws layout (floats): Zv[256*4*2048] | hs[8192*2048] | pub[2*2048 ull]
    // pub epochs: poison 0xAAAAAAAA never equals a live epoch (1..8192), and
    // ws is re-poisoned before every timed call -> no k_init needed.
    float* ws = (float*)d_ws;
    float* Zv = ws;
    float* hs = Zv + (size_t)VOCAB * 4 * HID;
    unsigned long long* pub = (unsigned long long*)(hs + (size_t)SEQ * HID);

    for (int g = 0; g < 4; ++g)
        k_zv<<<dim3(8, 8), dim3(256), 0, stream>>>(emb, W[g], B[g], C[g], Zv, g);

    float* outTail = out + (size_t)SEQ * ODIM;
    const float *Ui = U[0], *Uf = U[1], *Ugp = U[2], *Uo = U[3];
    const float* Zvc = Zv; const int* xc = x;
    unsigned long long* pubc = pub; float* hsc = hs; float* ot = outTail;
    void* args[9] = {&Ui, &Uf, &Ugp, &Uo, &Zvc, &xc, &pubc, &hsc, &ot};
    hipLaunchCooperativeKernel((void*)k_lstm, dim3(NBLK), dim3(NTHR), args, 0, stream);

    k_out<<<dim3(256), dim3(256), 0, stream>>>(hs, Vw, Vb, out);
}